// Round 13
// baseline (786.546 us; speedup 1.0000x reference)
//
#include <hip/hip_runtime.h>
#include <math.h>

// Problem constants (fixed by setup_inputs)
#define BB 8
#define NN 2048
#define HH 128
#define NSEG 8             // j-segments per node (256 j's each)
#define SEGJ 256
#define SEGCAP 12          // capacity per segment (Poisson mean ~1.1/seg)
#define MAXNBR (NSEG*SEGCAP)  // 96 per node
#define PREDL 10
#define TSTRIDE (NN*3)
#define OUT_BSTRIDE ((PREDL+1)*NN*3)

// R13 = R12 with the compile fix: k_adj's `states` is non-const (the
// step-0 init fold writes it). Otherwise identical to R12:
// (1) dense kernels at 1024 threads (same 512-block grids, 32-node tiles)
//     -> 32 waves/CU co-resident (was 16);
// (2) k_init folded into step-0 k_adj -> 40 dispatches.
// All pure lane remaps; per-output fmaf order / gather order unchanged ->
// bit-identical (absmax must stay exactly 0.03125).

// ---------------------------------------------------------------------------
// K1: radius-graph (R10/R11 body, bit-exact verified). 256 blocks x 512 thr;
// wave = one seg x 64 nodes -> pos[j] is ONE LDS address per wave.
// first!=0: stage pos from points, write states/out-t0/xs0 (init fold).
// ---------------------------------------------------------------------------
__global__ __launch_bounds__(512, 2) void k_adj(float* __restrict__ states,
                                                const float* __restrict__ points,
                                                float* __restrict__ xs0,
                                                float* __restrict__ dinv,
                                                int* __restrict__ nbr,
                                                int* __restrict__ cntN,
                                                float* __restrict__ out,
                                                int first) {
    const float R2c = 0.01f;
    int b = blockIdx.x & 7;
    int tile = blockIdx.x >> 3;     // 0..31 (64 nodes each)
    __shared__ float4 pos[NN];                  // 32 KiB
    __shared__ int degs[512];                   // 2 KiB
    __shared__ unsigned short jb[512][SEGCAP];  // 12 KiB
    const float* sb = states + (size_t)b * NN * 6;
    if (first) {
        const float* pb = points + (size_t)b * NN * 3;
        for (int j = threadIdx.x; j < NN; j += 512) {
            const float* r = pb + j * 3;
            pos[j] = make_float4(r[0], r[1], r[2], 0.f);
        }
    } else {
        for (int j = threadIdx.x; j < NN; j += 512) {
            const float* r = sb + j * 6;
            pos[j] = make_float4(r[0], r[1], r[2], 0.f);
        }
    }
    __syncthreads();
    int node = threadIdx.x & 63;
    int seg  = threadIdx.x >> 6;     // 0..7 == wave id
    int i = tile * 64 + node;
    int gi = b * NN + i;
    float4 pi = pos[i];
    int cnt = 0;
    int j0 = seg * SEGJ;
#pragma unroll 4
    for (int j = j0; j < j0 + SEGJ; ++j) {
        float4 pj = pos[j];
        float dx = pi.x - pj.x;
        float dy = pi.y - pj.y;
        float dz = pi.z - pj.z;
        // exact np order: (dx*dx + dy*dy) + dz*dz, each op rounded, no fma
        float d2 = __fadd_rn(__fadd_rn(__fmul_rn(dx, dx), __fmul_rn(dy, dy)),
                             __fmul_rn(dz, dz));
        if (d2 < R2c && j != i) {
            if (cnt < SEGCAP) jb[threadIdx.x][cnt] = (unsigned short)j;
            cnt++;
        }
    }
    if (cnt > SEGCAP) cnt = SEGCAP;
    degs[threadIdx.x] = cnt;        // tid == seg*64 + node
    __syncthreads();
    int off = 0;
    for (int s = 0; s < seg; ++s) off += degs[s * 64 + node];
    int base = gi * MAXNBR + off;
    for (int k = 0; k < cnt; ++k) nbr[base + k] = (int)jb[threadIdx.x][k];
    if (seg == NSEG - 1) {
        int tot = off + cnt;
        cntN[gi] = tot;
        float di = (float)(1.0 / sqrt((double)(1 + tot)));  // exact rsqrt
        dinv[gi] = di;
        float* xr = xs0 + (size_t)gi * 6;
        if (first) {
            // init fold: states0 = [points, 0]; out t=0; xs0 = di*states0
            float px = pi.x, py = pi.y, pz = pi.z;
            float* s = states + (size_t)gi * 6;
            s[0] = px; s[1] = py; s[2] = pz; s[3] = 0.f; s[4] = 0.f; s[5] = 0.f;
            float* o = out + (size_t)b * OUT_BSTRIDE + i * 3;
            o[0] = px; o[1] = py; o[2] = pz;
            xr[0] = di * px; xr[1] = di * py; xr[2] = di * pz;
            xr[3] = 0.f; xr[4] = 0.f; xr[5] = 0.f;   // di*0 == +0 bit-exact
        } else {
            const float* srow = sb + (size_t)i * 6;
#pragma unroll
            for (int c = 0; c < 6; ++c) xr[c] = di * srow[c];
        }
    }
}

// ---------------------------------------------------------------------------
// K2: layer 0 (6 -> 128). 512 blocks x 1024 thr: 32 nodes x 32 parts (4 ch).
// Same per-output fmaf order (k ascending) -> bit-identical.
// ---------------------------------------------------------------------------
__global__ __launch_bounds__(1024, 8) void k_l0(const float* __restrict__ xs0,
                                                const float* __restrict__ dinv,
                                                const int* __restrict__ nbr,
                                                const int* __restrict__ cntN,
                                                const float* __restrict__ W0,
                                                const float* __restrict__ b0,
                                                float* __restrict__ xs1) {
    int b = blockIdx.x & 7;
    int tile = blockIdx.x >> 3;
    int node = threadIdx.x >> 5;   // 0..31
    int part = threadIdx.x & 31;   // 4 ch each
    int i = tile * 32 + node;
    int gi = b * NN + i;
    float g[6];
    {
        const float* sr = xs0 + (size_t)gi * 6;
        float2 a0 = *(const float2*)sr;
        float2 a1 = *(const float2*)(sr + 2);
        float2 a2 = *(const float2*)(sr + 4);
        g[0] = a0.x; g[1] = a0.y; g[2] = a1.x; g[3] = a1.y; g[4] = a2.x; g[5] = a2.y;
    }
    int cnt = cntN[gi];
    const int* nb = nbr + gi * MAXNBR;
    for (int k = 0; k < cnt; ++k) {
        int j = nb[k];
        const float* xr = xs0 + (size_t)(b * NN + j) * 6;
        float2 v0 = *(const float2*)xr;
        float2 v1 = *(const float2*)(xr + 2);
        float2 v2 = *(const float2*)(xr + 4);
        g[0] += v0.x; g[1] += v0.y; g[2] += v1.x;
        g[3] += v1.y; g[4] += v2.x; g[5] += v2.y;
    }
    float di = dinv[gi];
#pragma unroll
    for (int c = 0; c < 6; ++c) g[c] *= di;
    int c0 = part * 4;
    float y[4];
    {
        float4 bv = *(const float4*)(b0 + c0);
        y[0] = bv.x; y[1] = bv.y; y[2] = bv.z; y[3] = bv.w;
    }
#pragma unroll
    for (int k = 0; k < 6; ++k) {
        float u = g[k];
        float4 w = *(const float4*)(W0 + k * HH + c0);
        y[0] = fmaf(u, w.x, y[0]);
        y[1] = fmaf(u, w.y, y[1]);
        y[2] = fmaf(u, w.z, y[2]);
        y[3] = fmaf(u, w.w, y[3]);
    }
    float* xo = xs1 + (size_t)gi * HH + c0;
    float4 v;
    v.x = di * fmaxf(y[0], 0.f);
    v.y = di * fmaxf(y[1], 0.f);
    v.z = di * fmaxf(y[2], 0.f);
    v.w = di * fmaxf(y[3], 0.f);
    *(float4*)xo = v;
}

// ---------------------------------------------------------------------------
// 128->128 layers: 512 blocks x 1024 thr, 32-node tiles, 32 waves/CU.
// Gather: thread = (node = t>>5, part = t&31, 4 ch). GEMM: thread = 1 node
// x ch {cA..cA+3}. W LDS panels double-buffered; W reads are 32-lane
// consecutive float4s (conflict-free); u reads 2-address broadcast.
// ---------------------------------------------------------------------------
__device__ __forceinline__ void gather_into_lds(const float* __restrict__ xin,
                                                const float* __restrict__ dinv,
                                                const int* __restrict__ nbr,
                                                const int* __restrict__ cntN,
                                                int b, int tile,
                                                float (*uS)[HH + 4]) {
    const int node = threadIdx.x >> 5;   // 0..31
    const int part = threadIdx.x & 31;   // 4 ch each
    const int i = tile * 32 + node;
    const int gi = b * NN + i;
    const int c0 = part * 4;
    float acc[4];
    *(float4*)acc = *(const float4*)(xin + (size_t)gi * HH + c0);
    const int cnt = cntN[gi];
    const int* nb = nbr + gi * MAXNBR;
    for (int k = 0; k < cnt; ++k) {
        const int j = nb[k];
        float v[4];
        *(float4*)v = *(const float4*)(xin + (size_t)(b * NN + j) * HH + c0);
        acc[0] += v[0]; acc[1] += v[1]; acc[2] += v[2]; acc[3] += v[3];
    }
    const float di = dinv[gi];
    float4 o;
    o.x = acc[0] * di; o.y = acc[1] * di; o.z = acc[2] * di; o.w = acc[3] * di;
    *(float4*)&uS[node][c0] = o;
}

// GEMM over one 32-row W panel in LDS. Thread owns 1 node x ch {cA..cA+3}.
// Per-output k-ascending fmaf order (p, r, q) identical to R11.
__device__ __forceinline__ void gemm_panel1(const float (*uS)[HH + 4],
                                            const float* __restrict__ wbuf,
                                            int p, int node, int cA,
                                            float y0[4]) {
#pragma unroll 2
    for (int r = 0; r < 32; r += 4) {
        float ua[4];
        *(float4*)ua = *(const float4*)(&uS[node][p * 32 + r]);
        const float* wrow = wbuf + r * HH + cA;
#pragma unroll
        for (int q = 0; q < 4; ++q) {
            float4 wa = *(const float4*)(wrow + q * HH);
            float u0 = ua[q];
            y0[0] = fmaf(u0, wa.x, y0[0]);
            y0[1] = fmaf(u0, wa.y, y0[1]);
            y0[2] = fmaf(u0, wa.z, y0[2]);
            y0[3] = fmaf(u0, wa.w, y0[3]);
        }
    }
}

// K3: middle layer (layer 1): xs_out = dinv * relu(u @ W + b)
__global__ __launch_bounds__(1024, 8) void k_mid(const float* __restrict__ xin,
                                                 const float* __restrict__ dinv,
                                                 const int* __restrict__ nbr,
                                                 const int* __restrict__ cntN,
                                                 const float* __restrict__ W,
                                                 const float* __restrict__ bias,
                                                 float* __restrict__ xout) {
    __shared__ __align__(16) float uS[32][HH + 4];   // 16.9 KB
    __shared__ __align__(16) float wS[2][32 * HH];   // 32 KB
    int b = blockIdx.x & 7;
    int tile = blockIdx.x >> 3;
    int t = threadIdx.x;
    const float4* Wf4 = (const float4*)W;
    float4 wreg = Wf4[t];   // panel 0 (1024 float4s)
    gather_into_lds(xin, dinv, nbr, cntN, b, tile, uS);
    ((float4*)wS[0])[t] = wreg;
    __syncthreads();
    int cb = t & 31, node = t >> 5;
    int cA = cb * 4;
    float y0[4];
    {
        float4 bv = *(const float4*)(bias + cA);
        y0[0] = bv.x; y0[1] = bv.y; y0[2] = bv.z; y0[3] = bv.w;
    }
#pragma unroll
    for (int p = 0; p < 4; ++p) {
        if (p < 3) wreg = Wf4[(p + 1) * 1024 + t];
        gemm_panel1(uS, wS[p & 1], p, node, cA, y0);
        if (p < 3) {
            ((float4*)wS[1 - (p & 1)])[t] = wreg;
            __syncthreads();
        }
    }
    int g0 = b * NN + tile * 32 + node;
    float di0 = dinv[g0];
    float* o0 = xout + (size_t)g0 * HH + cA;
    float4 va;
    va.x = di0 * fmaxf(y0[0], 0.f); va.y = di0 * fmaxf(y0[1], 0.f);
    va.z = di0 * fmaxf(y0[2], 0.f); va.w = di0 * fmaxf(y0[3], 0.f);
    *(float4*)o0 = va;
}

// K4: layer 2 + FC head + state update + output write.
// After the last panel, wS[0] is reused as y3[32][128] and wS[1] as wfcS.
__global__ __launch_bounds__(1024, 8) void k_last(const float* __restrict__ xin,
                                                  const float* __restrict__ dinv,
                                                  const int* __restrict__ nbr,
                                                  const int* __restrict__ cntN,
                                                  const float* __restrict__ W2,
                                                  const float* __restrict__ b2,
                                                  const float* __restrict__ Wfc,
                                                  const float* __restrict__ bfc,
                                                  const float* __restrict__ padding,
                                                  float* __restrict__ states,
                                                  float* __restrict__ outt) {
    __shared__ __align__(16) float uS[32][HH + 4];   // 16.9 KB
    __shared__ __align__(16) float wS[2][32 * HH];   // 32 KB
    int b = blockIdx.x & 7;
    int tile = blockIdx.x >> 3;
    int t = threadIdx.x;
    const float4* Wf4 = (const float4*)W2;
    float4 wreg = Wf4[t];
    gather_into_lds(xin, dinv, nbr, cntN, b, tile, uS);
    ((float4*)wS[0])[t] = wreg;
    __syncthreads();
    int cb = t & 31, node = t >> 5;
    int cA = cb * 4;
    float y0[4];
    {
        float4 bv = *(const float4*)(b2 + cA);
        y0[0] = bv.x; y0[1] = bv.y; y0[2] = bv.z; y0[3] = bv.w;
    }
#pragma unroll
    for (int p = 0; p < 4; ++p) {
        if (p < 3) wreg = Wf4[(p + 1) * 1024 + t];
        gemm_panel1(uS, wS[p & 1], p, node, cA, y0);
        if (p < 3) {
            ((float4*)wS[1 - (p & 1)])[t] = wreg;
            __syncthreads();
        }
    }
    __syncthreads();   // all panel reads done; reuse wS
    float* y3  = wS[0];   // [32][HH]
    float* wfc = wS[1];   // HH*6 floats
    for (int q = t; q < HH * 6; q += 1024) wfc[q] = Wfc[q];
    {
        float4 v;
        v.x = fmaxf(y0[0], 0.f); v.y = fmaxf(y0[1], 0.f);
        v.z = fmaxf(y0[2], 0.f); v.w = fmaxf(y0[3], 0.f);
        *(float4*)&y3[node * HH + cA] = v;
    }
    __syncthreads();
    if (t < 192) {
        int n = t / 6;
        int c = t - n * 6;
        float r = bfc[c];
        for (int k = 0; k < HH; k += 4) {
            float yv[4];
            *(float4*)yv = *(const float4*)&y3[n * HH + k];
            r = fmaf(yv[0], wfc[(k + 0) * 6 + c], r);
            r = fmaf(yv[1], wfc[(k + 1) * 6 + c], r);
            r = fmaf(yv[2], wfc[(k + 2) * 6 + c], r);
            r = fmaf(yv[3], wfc[(k + 3) * 6 + c], r);
        }
        int i = tile * 32 + n;
        int gi = b * NN + i;
        float pv = padding[b * NN + i];   // all-ones in this setup
        float s = states[(size_t)gi * 6 + c] + r * pv;
        states[(size_t)gi * 6 + c] = s;
        if (c < 3) outt[(size_t)b * OUT_BSTRIDE + i * 3 + c] = s;
    }
}

// ---------------------------------------------------------------------------
extern "C" void kernel_launch(void* const* d_in, const int* in_sizes, int n_in,
                              void* d_out, int out_size, void* d_ws, size_t ws_size,
                              hipStream_t stream) {
    (void)in_sizes; (void)n_in; (void)out_size; (void)ws_size;
    const float* points  = (const float*)d_in[0];
    const float* padding = (const float*)d_in[5];
    const float* W0  = (const float*)d_in[6];
    const float* b0  = (const float*)d_in[7];
    const float* W1  = (const float*)d_in[8];
    const float* b1  = (const float*)d_in[9];
    const float* W2  = (const float*)d_in[10];
    const float* b2  = (const float*)d_in[11];
    const float* Wfc = (const float*)d_in[12];
    const float* bfc = (const float*)d_in[13];
    float* out = (float*)d_out;

    // workspace carve-up (~24 MB)
    float* ws     = (float*)d_ws;
    float* states = ws;                       // BB*NN*6
    float* xs0    = states + BB * NN * 6;     // BB*NN*6
    float* xs1    = xs0 + BB * NN * 6;        // BB*NN*HH
    float* xs2    = xs1 + BB * NN * HH;       // BB*NN*HH
    float* dinvp  = xs2 + BB * NN * HH;       // BB*NN
    int*   nbr    = (int*)(dinvp + BB * NN);  // BB*NN*MAXNBR
    int*   cntN   = nbr + BB * NN * MAXNBR;   // BB*NN

    for (int t = 0; t < PREDL; ++t) {
        k_adj<<<256, 512, 0, stream>>>(states, points, xs0, dinvp, nbr, cntN,
                                       out, (t == 0) ? 1 : 0);
        k_l0<<<512, 1024, 0, stream>>>(xs0, dinvp, nbr, cntN, W0, b0, xs1);
        k_mid<<<512, 1024, 0, stream>>>(xs1, dinvp, nbr, cntN, W1, b1, xs2);
        k_last<<<512, 1024, 0, stream>>>(xs2, dinvp, nbr, cntN, W2, b2, Wfc, bfc,
                                         padding, states,
                                         out + (size_t)(t + 1) * TSTRIDE);
    }
}

// Round 14
// 778.385 us; speedup vs baseline: 1.0105x; 1.0105x over previous
//
#include <hip/hip_runtime.h>
#include <math.h>

// Problem constants (fixed by setup_inputs)
#define BB 8
#define NN 2048
#define HH 128
#define NSEG 8             // j-segments per node (256 j's each)
#define SEGJ 256
#define SEGCAP 12          // capacity per segment (Poisson mean ~1.1/seg)
#define MAXNBR (NSEG*SEGCAP)  // 96 per node
#define PREDL 10
#define TSTRIDE (NN*3)
#define OUT_BSTRIDE ((PREDL+1)*NN*3)

// R14 = exact revert to R11, the best verified configuration (779 us,
// absmax 0.03125). Occupancy curve mapped: 8 waves/CU (R10, 790) ->
// 16 (R11, 779) -> 32 (R13, 786.5). 16 waves/CU is the optimum.
// Structural floor: ~40 forced grid-sync boundaries (4 phases x 10
// sequential steps, 2-hop dataflow) + latency-bound scattered gathers.
// Falsified alternatives: software grid-sync (R5, 5x worse), cooperative
// launch (R4, rejected), recompute fusion (R8, 2x worse), LDS-issue cuts
// at lower occupancy (R9, worse), higher occupancy (R13, worse).

// ---------------------------------------------------------------------------
// K0: states0 = [points, 0]; write t=0 output slice
// ---------------------------------------------------------------------------
__global__ __launch_bounds__(256) void k_init(const float* __restrict__ points,
                                              float* __restrict__ states,
                                              float* __restrict__ out) {
    int idx = blockIdx.x * 256 + threadIdx.x;
    if (idx >= BB * NN) return;
    int b = idx >> 11;
    int n = idx & 2047;
    float px = points[idx * 3 + 0];
    float py = points[idx * 3 + 1];
    float pz = points[idx * 3 + 2];
    float* s = states + (size_t)idx * 6;
    s[0] = px; s[1] = py; s[2] = pz; s[3] = 0.f; s[4] = 0.f; s[5] = 0.f;
    float* o = out + (size_t)b * OUT_BSTRIDE + n * 3;
    o[0] = px; o[1] = py; o[2] = pz;
}

// ---------------------------------------------------------------------------
// K1: radius-graph (verbatim R10, bit-exact verified). 256 blocks x 512 thr;
// wave = one seg x 64 nodes -> pos[j] is ONE LDS address per wave.
// ---------------------------------------------------------------------------
__global__ __launch_bounds__(512, 2) void k_adj(const float* __restrict__ states,
                                                float* __restrict__ xs0,
                                                float* __restrict__ dinv,
                                                int* __restrict__ nbr,
                                                int* __restrict__ cntN) {
    const float R2c = 0.01f;
    int b = blockIdx.x & 7;
    int tile = blockIdx.x >> 3;     // 0..31 (64 nodes each)
    __shared__ float4 pos[NN];                  // 32 KiB
    __shared__ int degs[512];                   // 2 KiB
    __shared__ unsigned short jb[512][SEGCAP];  // 12 KiB
    const float* sb = states + (size_t)b * NN * 6;
    for (int j = threadIdx.x; j < NN; j += 512) {
        const float* r = sb + j * 6;
        pos[j] = make_float4(r[0], r[1], r[2], 0.f);
    }
    __syncthreads();
    int node = threadIdx.x & 63;
    int seg  = threadIdx.x >> 6;     // 0..7 == wave id
    int i = tile * 64 + node;
    int gi = b * NN + i;
    float4 pi = pos[i];
    int cnt = 0;
    int j0 = seg * SEGJ;
#pragma unroll 4
    for (int j = j0; j < j0 + SEGJ; ++j) {
        float4 pj = pos[j];
        float dx = pi.x - pj.x;
        float dy = pi.y - pj.y;
        float dz = pi.z - pj.z;
        // exact np order: (dx*dx + dy*dy) + dz*dz, each op rounded, no fma
        float d2 = __fadd_rn(__fadd_rn(__fmul_rn(dx, dx), __fmul_rn(dy, dy)),
                             __fmul_rn(dz, dz));
        if (d2 < R2c && j != i) {
            if (cnt < SEGCAP) jb[threadIdx.x][cnt] = (unsigned short)j;
            cnt++;
        }
    }
    if (cnt > SEGCAP) cnt = SEGCAP;
    degs[threadIdx.x] = cnt;        // tid == seg*64 + node
    __syncthreads();
    int off = 0;
    for (int s = 0; s < seg; ++s) off += degs[s * 64 + node];
    int base = gi * MAXNBR + off;
    for (int k = 0; k < cnt; ++k) nbr[base + k] = (int)jb[threadIdx.x][k];
    if (seg == NSEG - 1) {
        int tot = off + cnt;
        cntN[gi] = tot;
        float di = (float)(1.0 / sqrt((double)(1 + tot)));  // exact rsqrt
        dinv[gi] = di;
        const float* srow = sb + (size_t)i * 6;
        float* xr = xs0 + (size_t)gi * 6;
#pragma unroll
        for (int c = 0; c < 6; ++c) xr[c] = di * srow[c];
    }
}

// ---------------------------------------------------------------------------
// K2: layer 0 (6 -> 128). 512 blocks x 512 thr: 32 nodes x 16 parts (8 ch).
// Same per-output fmaf order (k ascending) -> bit-identical.
// ---------------------------------------------------------------------------
__global__ __launch_bounds__(512, 4) void k_l0(const float* __restrict__ xs0,
                                               const float* __restrict__ dinv,
                                               const int* __restrict__ nbr,
                                               const int* __restrict__ cntN,
                                               const float* __restrict__ W0,
                                               const float* __restrict__ b0,
                                               float* __restrict__ xs1) {
    int b = blockIdx.x & 7;
    int tile = blockIdx.x >> 3;
    int node = threadIdx.x >> 4;   // 0..31
    int part = threadIdx.x & 15;   // 8 ch each
    int i = tile * 32 + node;
    int gi = b * NN + i;
    float g[6];
    {
        const float* sr = xs0 + (size_t)gi * 6;
        float2 a0 = *(const float2*)sr;
        float2 a1 = *(const float2*)(sr + 2);
        float2 a2 = *(const float2*)(sr + 4);
        g[0] = a0.x; g[1] = a0.y; g[2] = a1.x; g[3] = a1.y; g[4] = a2.x; g[5] = a2.y;
    }
    int cnt = cntN[gi];
    const int* nb = nbr + gi * MAXNBR;
    for (int k = 0; k < cnt; ++k) {
        int j = nb[k];
        const float* xr = xs0 + (size_t)(b * NN + j) * 6;
        float2 v0 = *(const float2*)xr;
        float2 v1 = *(const float2*)(xr + 2);
        float2 v2 = *(const float2*)(xr + 4);
        g[0] += v0.x; g[1] += v0.y; g[2] += v1.x;
        g[3] += v1.y; g[4] += v2.x; g[5] += v2.y;
    }
    float di = dinv[gi];
#pragma unroll
    for (int c = 0; c < 6; ++c) g[c] *= di;
    int c0 = part * 8;
    float y[8];
#pragma unroll
    for (int r = 0; r < 2; ++r) {
        float4 bv = *(const float4*)(b0 + c0 + r * 4);
        y[r * 4 + 0] = bv.x; y[r * 4 + 1] = bv.y; y[r * 4 + 2] = bv.z; y[r * 4 + 3] = bv.w;
    }
#pragma unroll
    for (int k = 0; k < 6; ++k) {
        float u = g[k];
        const float* wr = W0 + k * HH + c0;
#pragma unroll
        for (int r = 0; r < 2; ++r) {
            float4 w = *(const float4*)(wr + r * 4);
            y[r * 4 + 0] = fmaf(u, w.x, y[r * 4 + 0]);
            y[r * 4 + 1] = fmaf(u, w.y, y[r * 4 + 1]);
            y[r * 4 + 2] = fmaf(u, w.z, y[r * 4 + 2]);
            y[r * 4 + 3] = fmaf(u, w.w, y[r * 4 + 3]);
        }
    }
    float* xo = xs1 + (size_t)gi * HH + c0;
#pragma unroll
    for (int r = 0; r < 2; ++r) {
        float4 v;
        v.x = di * fmaxf(y[r * 4 + 0], 0.f);
        v.y = di * fmaxf(y[r * 4 + 1], 0.f);
        v.z = di * fmaxf(y[r * 4 + 2], 0.f);
        v.w = di * fmaxf(y[r * 4 + 3], 0.f);
        *(float4*)(xo + r * 4) = v;
    }
}

// ---------------------------------------------------------------------------
// 128->128 layers: 512 blocks x 512 thr, 32-node tiles, 16 waves/CU.
// Gather: thread = (node = t>>4, part = t&15, 8 ch). GEMM: thread = 1 node
// x ch {cA..+3, cA+64..+67}. W LDS panels double-buffered, channel-
// interleaved (conflict-free, verified R6).
// ---------------------------------------------------------------------------
__device__ __forceinline__ void gather_into_lds(const float* __restrict__ xin,
                                                const float* __restrict__ dinv,
                                                const int* __restrict__ nbr,
                                                const int* __restrict__ cntN,
                                                int b, int tile,
                                                float (*uS)[HH + 4]) {
    const int node = threadIdx.x >> 4;   // 0..31
    const int part = threadIdx.x & 15;   // 8 ch each
    const int i = tile * 32 + node;
    const int gi = b * NN + i;
    const int c0 = part * 8;
    float acc[8];
    const float* xs = xin + (size_t)gi * HH + c0;
#pragma unroll
    for (int r = 0; r < 2; ++r) *(float4*)&acc[r * 4] = *(const float4*)(xs + r * 4);
    const int cnt = cntN[gi];
    const int* nb = nbr + gi * MAXNBR;
    for (int k = 0; k < cnt; ++k) {
        const int j = nb[k];
        const float* xr = xin + (size_t)(b * NN + j) * HH + c0;
#pragma unroll
        for (int r = 0; r < 2; ++r) {
            float v[4];
            *(float4*)v = *(const float4*)(xr + r * 4);
            acc[r * 4 + 0] += v[0]; acc[r * 4 + 1] += v[1];
            acc[r * 4 + 2] += v[2]; acc[r * 4 + 3] += v[3];
        }
    }
    const float di = dinv[gi];
#pragma unroll
    for (int r = 0; r < 2; ++r) {
        float4 o;
        o.x = acc[r * 4 + 0] * di; o.y = acc[r * 4 + 1] * di;
        o.z = acc[r * 4 + 2] * di; o.w = acc[r * 4 + 3] * di;
        *(float4*)&uS[node][c0 + r * 4] = o;
    }
}

// GEMM over one 32-row W panel in LDS. Thread owns 1 node x channels
// {cA..cA+3, cA+64..cA+67}. Same per-output k-ascending fmaf order.
__device__ __forceinline__ void gemm_panel1(const float (*uS)[HH + 4],
                                            const float* __restrict__ wbuf,
                                            int p, int node, int cA,
                                            float y0[8]) {
#pragma unroll 2
    for (int r = 0; r < 32; r += 4) {
        float ua[4];
        *(float4*)ua = *(const float4*)(&uS[node][p * 32 + r]);
        const float* wrow = wbuf + r * HH + cA;
#pragma unroll
        for (int q = 0; q < 4; ++q) {
            float4 wa = *(const float4*)(wrow + q * HH);        // ch cA..cA+3
            float4 wb = *(const float4*)(wrow + q * HH + 64);   // ch cA+64..
            float u0 = ua[q];
            y0[0] = fmaf(u0, wa.x, y0[0]); y0[1] = fmaf(u0, wa.y, y0[1]);
            y0[2] = fmaf(u0, wa.z, y0[2]); y0[3] = fmaf(u0, wa.w, y0[3]);
            y0[4] = fmaf(u0, wb.x, y0[4]); y0[5] = fmaf(u0, wb.y, y0[5]);
            y0[6] = fmaf(u0, wb.z, y0[6]); y0[7] = fmaf(u0, wb.w, y0[7]);
        }
    }
}

// K3: middle layer (layer 1): xs_out = dinv * relu(u @ W + b)
__global__ __launch_bounds__(512, 4) void k_mid(const float* __restrict__ xin,
                                                const float* __restrict__ dinv,
                                                const int* __restrict__ nbr,
                                                const int* __restrict__ cntN,
                                                const float* __restrict__ W,
                                                const float* __restrict__ bias,
                                                float* __restrict__ xout) {
    __shared__ __align__(16) float uS[32][HH + 4];   // 16.9 KB
    __shared__ __align__(16) float wS[2][32 * HH];   // 32 KB
    int b = blockIdx.x & 7;
    int tile = blockIdx.x >> 3;
    int t = threadIdx.x;
    const float4* Wf4 = (const float4*)W;
    float4 wreg[2];
    wreg[0] = Wf4[t]; wreg[1] = Wf4[t + 512];   // panel 0
    gather_into_lds(xin, dinv, nbr, cntN, b, tile, uS);
    {
        float4* ws4 = (float4*)wS[0];
        ws4[t] = wreg[0]; ws4[t + 512] = wreg[1];
    }
    __syncthreads();
    int cb = t & 15, node = t >> 4;
    int cA = cb * 4;
    float y0[8];
    {
        float4 bv0 = *(const float4*)(bias + cA);
        float4 bv1 = *(const float4*)(bias + cA + 64);
        y0[0] = bv0.x; y0[1] = bv0.y; y0[2] = bv0.z; y0[3] = bv0.w;
        y0[4] = bv1.x; y0[5] = bv1.y; y0[6] = bv1.z; y0[7] = bv1.w;
    }
#pragma unroll
    for (int p = 0; p < 4; ++p) {
        if (p < 3) {
            wreg[0] = Wf4[(p + 1) * 1024 + t];
            wreg[1] = Wf4[(p + 1) * 1024 + t + 512];
        }
        gemm_panel1(uS, wS[p & 1], p, node, cA, y0);
        if (p < 3) {
            float4* ws4 = (float4*)wS[1 - (p & 1)];
            ws4[t] = wreg[0]; ws4[t + 512] = wreg[1];
            __syncthreads();
        }
    }
    int g0 = b * NN + tile * 32 + node;
    float di0 = dinv[g0];
    float* o0 = xout + (size_t)g0 * HH + cA;
    float4 va, vb;
    va.x = di0 * fmaxf(y0[0], 0.f); va.y = di0 * fmaxf(y0[1], 0.f);
    va.z = di0 * fmaxf(y0[2], 0.f); va.w = di0 * fmaxf(y0[3], 0.f);
    vb.x = di0 * fmaxf(y0[4], 0.f); vb.y = di0 * fmaxf(y0[5], 0.f);
    vb.z = di0 * fmaxf(y0[6], 0.f); vb.w = di0 * fmaxf(y0[7], 0.f);
    *(float4*)o0 = va; *(float4*)(o0 + 64) = vb;
}

// K4: layer 2 + FC head + state update + output write.
// After the last panel, wS[0] is reused as y3[32][128] and wS[1] as wfcS.
__global__ __launch_bounds__(512, 4) void k_last(const float* __restrict__ xin,
                                                 const float* __restrict__ dinv,
                                                 const int* __restrict__ nbr,
                                                 const int* __restrict__ cntN,
                                                 const float* __restrict__ W2,
                                                 const float* __restrict__ b2,
                                                 const float* __restrict__ Wfc,
                                                 const float* __restrict__ bfc,
                                                 const float* __restrict__ padding,
                                                 float* __restrict__ states,
                                                 float* __restrict__ outt) {
    __shared__ __align__(16) float uS[32][HH + 4];   // 16.9 KB
    __shared__ __align__(16) float wS[2][32 * HH];   // 32 KB
    int b = blockIdx.x & 7;
    int tile = blockIdx.x >> 3;
    int t = threadIdx.x;
    const float4* Wf4 = (const float4*)W2;
    float4 wreg[2];
    wreg[0] = Wf4[t]; wreg[1] = Wf4[t + 512];
    gather_into_lds(xin, dinv, nbr, cntN, b, tile, uS);
    {
        float4* ws4 = (float4*)wS[0];
        ws4[t] = wreg[0]; ws4[t + 512] = wreg[1];
    }
    __syncthreads();
    int cb = t & 15, node = t >> 4;
    int cA = cb * 4;
    float y0[8];
    {
        float4 bv0 = *(const float4*)(b2 + cA);
        float4 bv1 = *(const float4*)(b2 + cA + 64);
        y0[0] = bv0.x; y0[1] = bv0.y; y0[2] = bv0.z; y0[3] = bv0.w;
        y0[4] = bv1.x; y0[5] = bv1.y; y0[6] = bv1.z; y0[7] = bv1.w;
    }
#pragma unroll
    for (int p = 0; p < 4; ++p) {
        if (p < 3) {
            wreg[0] = Wf4[(p + 1) * 1024 + t];
            wreg[1] = Wf4[(p + 1) * 1024 + t + 512];
        }
        gemm_panel1(uS, wS[p & 1], p, node, cA, y0);
        if (p < 3) {
            float4* ws4 = (float4*)wS[1 - (p & 1)];
            ws4[t] = wreg[0]; ws4[t + 512] = wreg[1];
            __syncthreads();
        }
    }
    __syncthreads();   // all panel reads done; reuse wS
    float* y3  = wS[0];   // [32][HH]
    float* wfc = wS[1];   // HH*6 floats
    for (int q = t; q < HH * 6; q += 512) wfc[q] = Wfc[q];
    {
        float4 v;
        v.x = fmaxf(y0[0], 0.f); v.y = fmaxf(y0[1], 0.f);
        v.z = fmaxf(y0[2], 0.f); v.w = fmaxf(y0[3], 0.f);
        *(float4*)&y3[node * HH + cA] = v;
        v.x = fmaxf(y0[4], 0.f); v.y = fmaxf(y0[5], 0.f);
        v.z = fmaxf(y0[6], 0.f); v.w = fmaxf(y0[7], 0.f);
        *(float4*)&y3[node * HH + cA + 64] = v;
    }
    __syncthreads();
    if (t < 192) {
        int n = t / 6;
        int c = t - n * 6;
        float r = bfc[c];
        for (int k = 0; k < HH; k += 4) {
            float yv[4];
            *(float4*)yv = *(const float4*)&y3[n * HH + k];
            r = fmaf(yv[0], wfc[(k + 0) * 6 + c], r);
            r = fmaf(yv[1], wfc[(k + 1) * 6 + c], r);
            r = fmaf(yv[2], wfc[(k + 2) * 6 + c], r);
            r = fmaf(yv[3], wfc[(k + 3) * 6 + c], r);
        }
        int i = tile * 32 + n;
        int gi = b * NN + i;
        float pv = padding[b * NN + i];   // all-ones in this setup
        float s = states[(size_t)gi * 6 + c] + r * pv;
        states[(size_t)gi * 6 + c] = s;
        if (c < 3) outt[(size_t)b * OUT_BSTRIDE + i * 3 + c] = s;
    }
}

// ---------------------------------------------------------------------------
extern "C" void kernel_launch(void* const* d_in, const int* in_sizes, int n_in,
                              void* d_out, int out_size, void* d_ws, size_t ws_size,
                              hipStream_t stream) {
    (void)in_sizes; (void)n_in; (void)out_size; (void)ws_size;
    const float* points  = (const float*)d_in[0];
    const float* padding = (const float*)d_in[5];
    const float* W0  = (const float*)d_in[6];
    const float* b0  = (const float*)d_in[7];
    const float* W1  = (const float*)d_in[8];
    const float* b1  = (const float*)d_in[9];
    const float* W2  = (const float*)d_in[10];
    const float* b2  = (const float*)d_in[11];
    const float* Wfc = (const float*)d_in[12];
    const float* bfc = (const float*)d_in[13];
    float* out = (float*)d_out;

    // workspace carve-up (~24 MB)
    float* ws     = (float*)d_ws;
    float* states = ws;                       // BB*NN*6
    float* xs0    = states + BB * NN * 6;     // BB*NN*6
    float* xs1    = xs0 + BB * NN * 6;        // BB*NN*HH
    float* xs2    = xs1 + BB * NN * HH;       // BB*NN*HH
    float* dinvp  = xs2 + BB * NN * HH;       // BB*NN
    int*   nbr    = (int*)(dinvp + BB * NN);  // BB*NN*MAXNBR
    int*   cntN   = nbr + BB * NN * MAXNBR;   // BB*NN

    k_init<<<(BB * NN) / 256, 256, 0, stream>>>(points, states, out);
    for (int t = 0; t < PREDL; ++t) {
        k_adj<<<256, 512, 0, stream>>>(states, xs0, dinvp, nbr, cntN);
        k_l0<<<512, 512, 0, stream>>>(xs0, dinvp, nbr, cntN, W0, b0, xs1);
        k_mid<<<512, 512, 0, stream>>>(xs1, dinvp, nbr, cntN, W1, b1, xs2);
        k_last<<<512, 512, 0, stream>>>(xs2, dinvp, nbr, cntN, W2, b2, Wfc, bfc,
                                        padding, states,
                                        out + (size_t)(t + 1) * TSTRIDE);
    }
}